// Round 10
// baseline (92.353 us; speedup 1.0000x reference)
//
#include <hip/hip_runtime.h>
#include <hip/hip_bf16.h>
#include <cstdint>
#include <cstddef>

#define A_DIM 128
#define T_DIM 2048
#define F_DIM 128
#define RBF_DIM 16
#define KDD 2048              // K-span per dd block (128 atoms x 16 rbf)
#define VT_LD 18432           // Vt row stride = 9 * KDD
#define NKG 32                // K-groups (A_DIM / 4)

typedef __attribute__((ext_vector_type(8))) short short8;
typedef __attribute__((ext_vector_type(4))) float f32x4;

__device__ __forceinline__ float silu_f(float x) {
    return x / (1.0f + __expf(-x));
}

// f32 -> bf16 bits, round-to-nearest-even (known-good from R4; do not swap
// for __float2bfloat16).
__device__ __forceinline__ unsigned short f2bf(float x) {
    union { float f; unsigned u; } v; v.f = x;
    unsigned r = v.u + 0x7FFFu + ((v.u >> 16) & 1u);
    return (unsigned short)(r >> 16);
}

// Grid-stride float4 zero for d_out (kept from R9: neutral but harmless).
__global__ void zero_kernel(float4* __restrict__ p, int n4) {
    const int stride = gridDim.x * blockDim.x;
    const float4 z = {0.f, 0.f, 0.f, 0.f};
    for (int i = blockIdx.x * blockDim.x + threadIdx.x; i < n4; i += stride)
        p[i] = z;
}

// grid (A/4, 3), block 512. h1/h2 MLP layers for 4 atoms, one output/thread/layer.
__global__ void mlp12_kernel(const float* __restrict__ feat0,
                             const float* __restrict__ w1, const float* __restrict__ b1,
                             const float* __restrict__ w2, const float* __restrict__ b2,
                             float* __restrict__ h2ws) {
    __shared__ float inv_s[4 * F_DIM];
    __shared__ float h_s[4 * F_DIM];
    const int i  = blockIdx.y;
    const int a0 = blockIdx.x * 4;
    const int tid = threadIdx.x;
    const int f  = tid & 127;
    const int la = tid >> 7;

    inv_s[tid] = feat0[(a0 + la) * F_DIM + f];
    __syncthreads();

    const float* w1i = w1 + (size_t)i * F_DIM * F_DIM;
    float x = b1[i * F_DIM + f];
    #pragma unroll 8
    for (int k = 0; k < F_DIM; ++k)
        x = fmaf(inv_s[la * F_DIM + k], w1i[k * F_DIM + f], x);
    h_s[tid] = silu_f(x);
    __syncthreads();

    const float* w2i = w2 + (size_t)i * F_DIM * F_DIM;
    float y = b2[i * F_DIM + f];
    #pragma unroll 8
    for (int k = 0; k < F_DIM; ++k)
        y = fmaf(h_s[la * F_DIM + k], w2i[k * F_DIM + f], y);
    h2ws[((size_t)i * A_DIM + a0 + la) * F_DIM + f] = silu_f(y);
}

// grid (A/4, 2, 3), block 256. Layer 3: (4 atoms)x(1024 cols) tile, 4x4 register tile.
// (R4-exact — known good.)
__global__ void mlp3_kernel(const float* __restrict__ h2ws,
                            const float* __restrict__ w3, const float* __restrict__ b3,
                            float* __restrict__ rbfws) {
    __shared__ float h2_s[4 * F_DIM];
    const int i  = blockIdx.z;
    const int a0 = blockIdx.x * 4;
    const int c0 = blockIdx.y * 1024;
    const int tid = threadIdx.x;

    for (int j = tid; j < 4 * F_DIM; j += 256)
        h2_s[j] = h2ws[((size_t)i * A_DIM + a0) * F_DIM + j];
    __syncthreads();

    const int c = c0 + tid * 4;
    const float* w3i = w3 + (size_t)i * F_DIM * 2048;
    float val[4][4];
    #pragma unroll
    for (int a = 0; a < 4; ++a) {
        #pragma unroll
        for (int cc = 0; cc < 4; ++cc)
            val[a][cc] = b3[i * 2048 + c + cc];
    }
    for (int k = 0; k < F_DIM; ++k) {
        const float4 w = *reinterpret_cast<const float4*>(&w3i[(size_t)k * 2048 + c]);
        #pragma unroll
        for (int a = 0; a < 4; ++a) {
            const float h = h2_s[a * F_DIM + k];
            val[a][0] = fmaf(h, w.x, val[a][0]);
            val[a][1] = fmaf(h, w.y, val[a][1]);
            val[a][2] = fmaf(h, w.z, val[a][2]);
            val[a][3] = fmaf(h, w.w, val[a][3]);
        }
    }
    const float inv_rbf = 0.25f;  // 1/sqrt(16)
    #pragma unroll
    for (int a = 0; a < 4; ++a) {
        float4 o;
        o.x = val[a][0] * inv_rbf;
        o.y = val[a][1] * inv_rbf;
        o.z = val[a][2] * inv_rbf;
        o.w = val[a][3] * inv_rbf;
        *reinterpret_cast<float4*>(&rbfws[((size_t)i * A_DIM + a0 + a) * 2048 + c]) = o;
    }
}

// Build Vt[f][k] bf16, k = dd*2048 + n*16 + r. (R4-exact.)
__global__ void build_vt_kernel(const float* __restrict__ feat0,
                                const float* __restrict__ feat1,
                                const float* __restrict__ feat2,
                                const float* __restrict__ rbfws,
                                unsigned short* __restrict__ Vt) {
    const int n  = blockIdx.x;
    const int dd = blockIdx.y;
    const int f  = threadIdx.x;

    int i, d;
    float fv;
    if (dd == 0)      { i = 0; d = 0;      fv = feat0[n * F_DIM + f]; }
    else if (dd < 4)  { i = 1; d = dd - 1; fv = feat1[(n * F_DIM + f) * 3 + d]; }
    else              { i = 2; d = dd - 4; fv = feat2[(n * F_DIM + f) * 5 + d]; }

    const float* rb = rbfws + ((size_t)(i * A_DIM + n) * RBF_DIM) * F_DIM + f;
    unsigned short* vp = Vt + (size_t)f * VT_LD + (size_t)dd * KDD + n * 16;
    #pragma unroll
    for (int r = 0; r < RBF_DIM; ++r)
        vp[r] = f2bf(fv * rb[(size_t)r * F_DIM]);
}

// MFMA GEMM — R8 body with M_rep 4->2 (ONLY change: wave tile 64tx64f ->
// 32tx64f, grid.x 16->32 => 1024 blocks = 4 waves/SIMD, was 2).
// Monolithic dd-loop (#pragma unroll 1) kept verbatim — the hand-unrolled
// template pipeline (R5-R7) failed correctness three times; do not reintroduce.
// grid (32 mt, 32 kg), block 256 = 4 waves in 2x2.
// k = dd*2048 + n*16 + r ; per block: 4 atoms (K-slice 9 dd x 64).
template<int MODE>
__global__ void __launch_bounds__(256) gemm_kernel(
        const float* __restrict__ sph0, const float* __restrict__ sph1,
        const float* __restrict__ sph2, const float* __restrict__ radial,
        const unsigned short* __restrict__ Vt,
        float* __restrict__ outbuf) {
    const int lane = threadIdx.x & 63;
    const int w    = threadIdx.x >> 6;
    const int wr   = w >> 1;            // wave row (t)
    const int wc   = w & 1;             // wave col (f)
    const int t0   = blockIdx.x * 64 + wr * 32;
    const int n0   = blockIdx.y * 4;
    const int kq   = lane >> 4;         // 0..3
    const int lf   = lane & 15;

    // Per-lane (m,ks) atom/r mapping for A-frags: k_local = 32*ks + 8*kq + j
    //  -> atom na = 2*ks + (kq>>1), r = (kq&1)*8 + j (j contiguous 0..7).
    // radial is dd-invariant: preload once, reuse for all 9 dd.
    f32x4 rad[2][2][2];
    #pragma unroll
    for (int m = 0; m < 2; ++m) {
        const int t = t0 + 16 * m + lf;
        #pragma unroll
        for (int ks = 0; ks < 2; ++ks) {
            const int n = n0 + 2 * ks + (kq >> 1);
            const float* rp = radial + ((size_t)n * T_DIM + t) * 16 + (kq & 1) * 8;
            rad[m][ks][0] = *reinterpret_cast<const f32x4*>(rp);
            rad[m][ks][1] = *reinterpret_cast<const f32x4*>(rp + 4);
        }
    }

    // Vt row base pointers per nf (k part added per dd/ks)
    const unsigned short* vrow[4];
    #pragma unroll
    for (int nf = 0; nf < 4; ++nf) {
        const int f = wc * 64 + 16 * nf + lf;
        vrow[nf] = Vt + (size_t)f * VT_LD + (size_t)n0 * 16 + 8 * kq;
    }

    f32x4 acc[2][4];
    #pragma unroll
    for (int m = 0; m < 2; ++m)
        #pragma unroll
        for (int nf = 0; nf < 4; ++nf)
            acc[m][nf] = (f32x4){0.f, 0.f, 0.f, 0.f};

    #pragma unroll 1
    for (int dd = 0; dd < 9; ++dd) {
        // uniform sph array select
        const float* sp; int smul, soff;
        if (dd == 0)     { sp = sph0; smul = 1; soff = 0; }
        else if (dd < 4) { sp = sph1; smul = 3; soff = dd - 1; }
        else             { sp = sph2; smul = 5; soff = dd - 4; }

        // B-fragments for this dd: [ks][nf]
        short8 b[2][4];
        const size_t koff = (size_t)dd * KDD;
        #pragma unroll
        for (int nf = 0; nf < 4; ++nf) {
            #pragma unroll
            for (int ks = 0; ks < 2; ++ks)
                b[ks][nf] = *reinterpret_cast<const short8*>(vrow[nf] + koff + 32 * ks);
        }

        // A-fragments built in regs, then 16x16x32 MFMAs
        #pragma unroll
        for (int m = 0; m < 2; ++m) {
            const int t = t0 + 16 * m + lf;
            #pragma unroll
            for (int ks = 0; ks < 2; ++ks) {
                const int n = n0 + 2 * ks + (kq >> 1);
                const float s = sp[((size_t)n * T_DIM + t) * smul + soff];
                short8 a;
                #pragma unroll
                for (int j = 0; j < 4; ++j) {
                    a[j]     = (short)f2bf(s * rad[m][ks][0][j]);
                    a[j + 4] = (short)f2bf(s * rad[m][ks][1][j]);
                }
                #pragma unroll
                for (int nf = 0; nf < 4; ++nf)
                    acc[m][nf] = __builtin_amdgcn_mfma_f32_16x16x32_bf16(
                        a, b[ks][nf], acc[m][nf], 0, 0, 0);
            }
        }
    }

    // Epilogue. C/D layout col=lane&15, row=(lane>>4)*4+reg (HW-verified in R4).
    float* pb = (MODE == 0)
        ? outbuf + (size_t)blockIdx.y * (T_DIM * F_DIM)   // own slice, plain stores
        : outbuf;                                          // shared, atomics
    #pragma unroll
    for (int m = 0; m < 2; ++m) {
        #pragma unroll
        for (int nf = 0; nf < 4; ++nf) {
            const int f = wc * 64 + 16 * nf + lf;
            #pragma unroll
            for (int reg = 0; reg < 4; ++reg) {
                const int t = t0 + 16 * m + 4 * kq + reg;
                if (MODE == 0)
                    pb[(size_t)t * F_DIM + f] = acc[m][nf][reg];
                else
                    atomicAdd(&pb[(size_t)t * F_DIM + f], acc[m][nf][reg]);
            }
        }
    }
}

// Plain path: sum 32 partial slices, then indexed atomicAdd into out.
// grid (T/2), block 256.
__global__ void scatter_sum_kernel(const float* __restrict__ partial,
                                   const int* __restrict__ tidx,
                                   float* __restrict__ out) {
    const int tid = threadIdx.x;
    const int t = blockIdx.x * 2 + (tid >> 7);
    const int f = tid & 127;
    const int g = tidx[t];
    const float* p = partial + (size_t)t * F_DIM + f;
    float s = 0.0f;
    #pragma unroll
    for (int kg = 0; kg < NKG; ++kg)
        s += p[(size_t)kg * (T_DIM * F_DIM)];
    atomicAdd(&out[(size_t)g * F_DIM + f], s);
}

// Fallback path (R4-exact): scatter sparse rows into d_out.
__global__ void scatter_kernel(const float* __restrict__ sparse,
                               const int* __restrict__ tidx,
                               float* __restrict__ out) {
    const int tid = threadIdx.x;
    const int t = blockIdx.x * 2 + (tid >> 7);
    const int f = tid & 127;
    const int g = tidx[t];
    atomicAdd(&out[(size_t)g * F_DIM + f], sparse[(size_t)t * F_DIM + f]);
}

extern "C" void kernel_launch(void* const* d_in, const int* in_sizes, int n_in,
                              void* d_out, int out_size, void* d_ws, size_t ws_size,
                              hipStream_t stream) {
    const float* feat0  = (const float*)d_in[0];
    const float* feat1  = (const float*)d_in[1];
    const float* feat2  = (const float*)d_in[2];
    const float* sph0   = (const float*)d_in[3];
    const float* sph1   = (const float*)d_in[4];
    const float* sph2   = (const float*)d_in[5];
    const float* radial = (const float*)d_in[6];
    const float* w1     = (const float*)d_in[7];
    const float* b1     = (const float*)d_in[8];
    const float* w2     = (const float*)d_in[9];
    const float* b2     = (const float*)d_in[10];
    const float* w3     = (const float*)d_in[11];
    const float* b3     = (const float*)d_in[12];
    const int*   tidx   = (const int*)d_in[13];
    float* out = (float*)d_out;

    // Common ws prefix: rbfws 3 MB | h2ws 192 KB
    float* rbfws  = (float*)d_ws;
    float* h2ws   = rbfws + 3 * A_DIM * RBF_DIM * F_DIM;

    // Plain path needs: prefix + Vt (4.5 MB) + partial (32 MB) ~= 41.7 MB
    const size_t plain_need =
        (size_t)(3 * A_DIM * RBF_DIM * F_DIM + 3 * A_DIM * F_DIM) * sizeof(float) +
        (size_t)F_DIM * VT_LD * sizeof(unsigned short) +
        (size_t)NKG * T_DIM * F_DIM * sizeof(float);
    const bool plain = (ws_size >= plain_need);

    zero_kernel<<<2048, 256, 0, stream>>>((float4*)out, out_size / 4);

    mlp12_kernel<<<dim3(A_DIM / 4, 3), 512, 0, stream>>>(feat0, w1, b1, w2, b2, h2ws);
    mlp3_kernel<<<dim3(A_DIM / 4, 2, 3), 256, 0, stream>>>(h2ws, w3, b3, rbfws);

    if (plain) {
        unsigned short* Vt = (unsigned short*)(h2ws + 3 * A_DIM * F_DIM);
        float* partial = (float*)(Vt + (size_t)F_DIM * VT_LD);
        build_vt_kernel<<<dim3(A_DIM, 9), 128, 0, stream>>>(feat0, feat1, feat2, rbfws, Vt);
        gemm_kernel<0><<<dim3(T_DIM / 64, A_DIM / 4), 256, 0, stream>>>(
            sph0, sph1, sph2, radial, Vt, partial);
        scatter_sum_kernel<<<dim3(T_DIM / 2), 256, 0, stream>>>(partial, tidx, out);
    } else {
        // R4-exact fallback layout: rbfws | h2ws | sparse | Vt
        float* sparse = h2ws + 3 * A_DIM * F_DIM;
        unsigned short* Vt = (unsigned short*)(sparse + T_DIM * F_DIM);
        hipMemsetAsync(sparse, 0, (size_t)T_DIM * F_DIM * sizeof(float), stream);
        build_vt_kernel<<<dim3(A_DIM, 9), 128, 0, stream>>>(feat0, feat1, feat2, rbfws, Vt);
        gemm_kernel<1><<<dim3(T_DIM / 64, A_DIM / 4), 256, 0, stream>>>(
            sph0, sph1, sph2, radial, Vt, sparse);
        scatter_kernel<<<dim3(T_DIM / 2), 256, 0, stream>>>(sparse, tidx, out);
    }
}

// Round 11
// 74.506 us; speedup vs baseline: 1.2395x; 1.2395x over previous
//
#include <hip/hip_runtime.h>
#include <hip/hip_bf16.h>
#include <cstdint>
#include <cstddef>

#define A_DIM 128
#define T_DIM 2048
#define F_DIM 128
#define RBF_DIM 16
#define KDD 2048              // K-span per dd block (128 atoms x 16 rbf)
#define VT_LD 18432           // Vt row stride = 9 * KDD
#define NKG 32                // K-groups (A_DIM / 4)
#define BT 64                 // t-span per gemm block

typedef __attribute__((ext_vector_type(8))) short short8;
typedef __attribute__((ext_vector_type(4))) float f32x4;

__device__ __forceinline__ float silu_f(float x) {
    return x / (1.0f + __expf(-x));
}

// f32 -> bf16 bits, round-to-nearest-even (known-good from R4; do not swap
// for __float2bfloat16).
__device__ __forceinline__ unsigned short f2bf(float x) {
    union { float f; unsigned u; } v; v.f = x;
    unsigned r = v.u + 0x7FFFu + ((v.u >> 16) & 1u);
    return (unsigned short)(r >> 16);
}

// async global->LDS, 16 B per lane; LDS dest is wave-uniform base + lane*16.
__device__ __forceinline__ void gl_lds16(const void* g, void* l) {
    __builtin_amdgcn_global_load_lds(
        (const __attribute__((address_space(1))) void*)g,
        (__attribute__((address_space(3))) void*)l, 16, 0, 0);
}

// Grid-stride float4 zero for d_out.
__global__ void zero_kernel(float4* __restrict__ p, int n4) {
    const int stride = gridDim.x * blockDim.x;
    const float4 z = {0.f, 0.f, 0.f, 0.f};
    for (int i = blockIdx.x * blockDim.x + threadIdx.x; i < n4; i += stride)
        p[i] = z;
}

// grid (A/4, 3), block 512. h1/h2 MLP layers for 4 atoms, one output/thread/layer.
__global__ void mlp12_kernel(const float* __restrict__ feat0,
                             const float* __restrict__ w1, const float* __restrict__ b1,
                             const float* __restrict__ w2, const float* __restrict__ b2,
                             float* __restrict__ h2ws) {
    __shared__ float inv_s[4 * F_DIM];
    __shared__ float h_s[4 * F_DIM];
    const int i  = blockIdx.y;
    const int a0 = blockIdx.x * 4;
    const int tid = threadIdx.x;
    const int f  = tid & 127;
    const int la = tid >> 7;

    inv_s[tid] = feat0[(a0 + la) * F_DIM + f];
    __syncthreads();

    const float* w1i = w1 + (size_t)i * F_DIM * F_DIM;
    float x = b1[i * F_DIM + f];
    #pragma unroll 8
    for (int k = 0; k < F_DIM; ++k)
        x = fmaf(inv_s[la * F_DIM + k], w1i[k * F_DIM + f], x);
    h_s[tid] = silu_f(x);
    __syncthreads();

    const float* w2i = w2 + (size_t)i * F_DIM * F_DIM;
    float y = b2[i * F_DIM + f];
    #pragma unroll 8
    for (int k = 0; k < F_DIM; ++k)
        y = fmaf(h_s[la * F_DIM + k], w2i[k * F_DIM + f], y);
    h2ws[((size_t)i * A_DIM + a0 + la) * F_DIM + f] = silu_f(y);
}

// grid (A/4, 2, 3), block 256. Layer 3: (4 atoms)x(1024 cols) tile, 4x4 register tile.
__global__ void mlp3_kernel(const float* __restrict__ h2ws,
                            const float* __restrict__ w3, const float* __restrict__ b3,
                            float* __restrict__ rbfws) {
    __shared__ float h2_s[4 * F_DIM];
    const int i  = blockIdx.z;
    const int a0 = blockIdx.x * 4;
    const int c0 = blockIdx.y * 1024;
    const int tid = threadIdx.x;

    for (int j = tid; j < 4 * F_DIM; j += 256)
        h2_s[j] = h2ws[((size_t)i * A_DIM + a0) * F_DIM + j];
    __syncthreads();

    const int c = c0 + tid * 4;
    const float* w3i = w3 + (size_t)i * F_DIM * 2048;
    float val[4][4];
    #pragma unroll
    for (int a = 0; a < 4; ++a) {
        #pragma unroll
        for (int cc = 0; cc < 4; ++cc)
            val[a][cc] = b3[i * 2048 + c + cc];
    }
    for (int k = 0; k < F_DIM; ++k) {
        const float4 w = *reinterpret_cast<const float4*>(&w3i[(size_t)k * 2048 + c]);
        #pragma unroll
        for (int a = 0; a < 4; ++a) {
            const float h = h2_s[a * F_DIM + k];
            val[a][0] = fmaf(h, w.x, val[a][0]);
            val[a][1] = fmaf(h, w.y, val[a][1]);
            val[a][2] = fmaf(h, w.z, val[a][2]);
            val[a][3] = fmaf(h, w.w, val[a][3]);
        }
    }
    const float inv_rbf = 0.25f;  // 1/sqrt(16)
    #pragma unroll
    for (int a = 0; a < 4; ++a) {
        float4 o;
        o.x = val[a][0] * inv_rbf;
        o.y = val[a][1] * inv_rbf;
        o.z = val[a][2] * inv_rbf;
        o.w = val[a][3] * inv_rbf;
        *reinterpret_cast<float4*>(&rbfws[((size_t)i * A_DIM + a0 + a) * 2048 + c]) = o;
    }
}

// Build Vt[f][k] bf16, k = dd*2048 + n*16 + r. (R4-exact.)
__global__ void build_vt_kernel(const float* __restrict__ feat0,
                                const float* __restrict__ feat1,
                                const float* __restrict__ feat2,
                                const float* __restrict__ rbfws,
                                unsigned short* __restrict__ Vt) {
    const int n  = blockIdx.x;
    const int dd = blockIdx.y;
    const int f  = threadIdx.x;

    int i, d;
    float fv;
    if (dd == 0)      { i = 0; d = 0;      fv = feat0[n * F_DIM + f]; }
    else if (dd < 4)  { i = 1; d = dd - 1; fv = feat1[(n * F_DIM + f) * 3 + d]; }
    else              { i = 2; d = dd - 4; fv = feat2[(n * F_DIM + f) * 5 + d]; }

    const float* rb = rbfws + ((size_t)(i * A_DIM + n) * RBF_DIM) * F_DIM + f;
    unsigned short* vp = Vt + (size_t)f * VT_LD + (size_t)dd * KDD + n * 16;
    #pragma unroll
    for (int r = 0; r < RBF_DIM; ++r)
        vp[r] = f2bf(fv * rb[(size_t)r * F_DIM]);
}

// MFMA GEMM — R10 body with ONE change: B-tile + sph staged through LDS per
// dd-step (global_load_lds width=16, two barriers), replacing the per-lane
// global gathers that kept the kernel latency-bound at MfmaUtil 6%.
// Swizzle discipline (rule #21): LINEAR gl_lds dest + PRE-SWIZZLED global
// source chunk c' = c ^ (f&7) + swizzled ds_read addr. Monolithic dd-loop —
// template pipelines failed 3/3 (R5-R7); do not reintroduce.
// grid (32 mt, 32 kg), block 256 = 4 waves in 2x2 (wave tile 32t x 64f).
// k = dd*2048 + n*16 + r ; per block: 4 atoms (K-slice 9 dd x 64).
template<int MODE>
__global__ void __launch_bounds__(256) gemm_kernel(
        const float* __restrict__ sph0, const float* __restrict__ sph1,
        const float* __restrict__ sph2, const float* __restrict__ radial,
        const unsigned short* __restrict__ Vt,
        float* __restrict__ outbuf) {
    __shared__ unsigned short b_s[F_DIM * 64];   // 16 KB: [f][chunk^(f&7)] 8-elem chunks
    __shared__ float sph_s[4 * BT];              // 1 KB: [nn][tt]

    const int tid  = threadIdx.x;
    const int lane = tid & 63;
    const int w    = tid >> 6;
    const int wr   = w >> 1;            // wave row (t)
    const int wc   = w & 1;             // wave col (f)
    const int t0   = blockIdx.x * BT + wr * 32;
    const int n0   = blockIdx.y * 4;
    const int kq   = lane >> 4;         // 0..3
    const int lf   = lane & 15;

    // radial is dd-invariant: preload once to regs (R10-exact).
    // k_local = 32*ks + 8*kq + j -> atom n0 + 2*ks + (kq>>1), r = (kq&1)*8 + j.
    f32x4 rad[2][2][2];
    #pragma unroll
    for (int m = 0; m < 2; ++m) {
        const int t = t0 + 16 * m + lf;
        #pragma unroll
        for (int ks = 0; ks < 2; ++ks) {
            const int n = n0 + 2 * ks + (kq >> 1);
            const float* rp = radial + ((size_t)n * T_DIM + t) * 16 + (kq & 1) * 8;
            rad[m][ks][0] = *reinterpret_cast<const f32x4*>(rp);
            rad[m][ks][1] = *reinterpret_cast<const f32x4*>(rp + 4);
        }
    }

    // B staging source (per thread, per issue q of 4): global element index
    // i = q*256 + tid; row f = q*32 + tid/8; chunk c' = (tid%8) ^ ((tid/8)&7)
    // (pre-swizzled so the linear LDS write lands swizzled).
    const int fs_row = tid >> 3;                                  // 0..31
    const int cs     = (tid & 7) ^ ((tid >> 3) & 7);
    const unsigned short* gsrc0 = Vt + (size_t)fs_row * VT_LD + n0 * 16 + cs * 8;
    // sph staging: thread tid -> sph_s[nn*BT+tt], nn = tid/64, tt = tid%64
    const int nn_s = tid >> 6;
    const int tt_s = tid & 63;
    const size_t sph_tbase = (size_t)(n0 + nn_s) * T_DIM + blockIdx.x * BT + tt_s;

    f32x4 acc[2][4];
    #pragma unroll
    for (int m = 0; m < 2; ++m)
        #pragma unroll
        for (int nf = 0; nf < 4; ++nf)
            acc[m][nf] = (f32x4){0.f, 0.f, 0.f, 0.f};

    #pragma unroll 1
    for (int dd = 0; dd < 9; ++dd) {
        // uniform sph array select (R4-proven runtime select)
        const float* sp; int smul, soff;
        if (dd == 0)     { sp = sph0; smul = 1; soff = 0; }
        else if (dd < 4) { sp = sph1; smul = 3; soff = dd - 1; }
        else             { sp = sph2; smul = 5; soff = dd - 4; }

        __syncthreads();   // previous iteration done reading LDS

        // stage B-tile: 4 issues x (256 lanes x 16 B) = 16 KB, linear LDS dest
        const size_t koff = (size_t)dd * KDD;
        #pragma unroll
        for (int q = 0; q < 4; ++q) {
            const unsigned short* gp = gsrc0 + koff + (size_t)(q * 32) * VT_LD;
            void* lp = (void*)((char*)b_s + q * 4096 + w * 1024);
            gl_lds16(gp, lp);
        }
        // stage sph tile (256 floats)
        sph_s[tid] = sp[sph_tbase * smul + soff];

        __syncthreads();   // compiler drains vmcnt+lgkmcnt before s_barrier

        // B-fragments from LDS (swizzled read): chunk cw = 4*ks+kq at row f
        short8 bfr[2][4];
        #pragma unroll
        for (int ks = 0; ks < 2; ++ks) {
            #pragma unroll
            for (int nf = 0; nf < 4; ++nf) {
                const int f = wc * 64 + 16 * nf + lf;
                const int byte = f * 128 + (((ks * 4 + kq) ^ (lf & 7)) * 16);
                bfr[ks][nf] = *reinterpret_cast<const short8*>((const char*)b_s + byte);
            }
        }

        // A-fragments built in regs, then 16x16x32 MFMAs (R10-exact math)
        #pragma unroll
        for (int m = 0; m < 2; ++m) {
            #pragma unroll
            for (int ks = 0; ks < 2; ++ks) {
                const float s = sph_s[(2 * ks + (kq >> 1)) * BT + wr * 32 + 16 * m + lf];
                short8 a;
                #pragma unroll
                for (int j = 0; j < 4; ++j) {
                    a[j]     = (short)f2bf(s * rad[m][ks][0][j]);
                    a[j + 4] = (short)f2bf(s * rad[m][ks][1][j]);
                }
                #pragma unroll
                for (int nf = 0; nf < 4; ++nf)
                    acc[m][nf] = __builtin_amdgcn_mfma_f32_16x16x32_bf16(
                        a, bfr[ks][nf], acc[m][nf], 0, 0, 0);
            }
        }
    }

    // Epilogue. C/D layout col=lane&15, row=(lane>>4)*4+reg (HW-verified in R4).
    float* pb = (MODE == 0)
        ? outbuf + (size_t)blockIdx.y * (T_DIM * F_DIM)   // own slice, plain stores
        : outbuf;                                          // shared, atomics
    #pragma unroll
    for (int m = 0; m < 2; ++m) {
        #pragma unroll
        for (int nf = 0; nf < 4; ++nf) {
            const int f = wc * 64 + 16 * nf + lf;
            #pragma unroll
            for (int reg = 0; reg < 4; ++reg) {
                const int t = t0 + 16 * m + 4 * kq + reg;
                if (MODE == 0)
                    pb[(size_t)t * F_DIM + f] = acc[m][nf][reg];
                else
                    atomicAdd(&pb[(size_t)t * F_DIM + f], acc[m][nf][reg]);
            }
        }
    }
}

// Plain path: sum 32 partial slices, then indexed atomicAdd into out.
// grid (T/2), block 256.
__global__ void scatter_sum_kernel(const float* __restrict__ partial,
                                   const int* __restrict__ tidx,
                                   float* __restrict__ out) {
    const int tid = threadIdx.x;
    const int t = blockIdx.x * 2 + (tid >> 7);
    const int f = tid & 127;
    const int g = tidx[t];
    const float* p = partial + (size_t)t * F_DIM + f;
    float s = 0.0f;
    #pragma unroll
    for (int kg = 0; kg < NKG; ++kg)
        s += p[(size_t)kg * (T_DIM * F_DIM)];
    atomicAdd(&out[(size_t)g * F_DIM + f], s);
}

// Fallback path (R4-exact): scatter sparse rows into d_out.
__global__ void scatter_kernel(const float* __restrict__ sparse,
                               const int* __restrict__ tidx,
                               float* __restrict__ out) {
    const int tid = threadIdx.x;
    const int t = blockIdx.x * 2 + (tid >> 7);
    const int f = tid & 127;
    const int g = tidx[t];
    atomicAdd(&out[(size_t)g * F_DIM + f], sparse[(size_t)t * F_DIM + f]);
}

extern "C" void kernel_launch(void* const* d_in, const int* in_sizes, int n_in,
                              void* d_out, int out_size, void* d_ws, size_t ws_size,
                              hipStream_t stream) {
    const float* feat0  = (const float*)d_in[0];
    const float* feat1  = (const float*)d_in[1];
    const float* feat2  = (const float*)d_in[2];
    const float* sph0   = (const float*)d_in[3];
    const float* sph1   = (const float*)d_in[4];
    const float* sph2   = (const float*)d_in[5];
    const float* radial = (const float*)d_in[6];
    const float* w1     = (const float*)d_in[7];
    const float* b1     = (const float*)d_in[8];
    const float* w2     = (const float*)d_in[9];
    const float* b2     = (const float*)d_in[10];
    const float* w3     = (const float*)d_in[11];
    const float* b3     = (const float*)d_in[12];
    const int*   tidx   = (const int*)d_in[13];
    float* out = (float*)d_out;

    // Common ws prefix: rbfws 3 MB | h2ws 192 KB
    float* rbfws  = (float*)d_ws;
    float* h2ws   = rbfws + 3 * A_DIM * RBF_DIM * F_DIM;

    // Plain path needs: prefix + Vt (4.5 MB) + partial (32 MB) ~= 41.7 MB
    const size_t plain_need =
        (size_t)(3 * A_DIM * RBF_DIM * F_DIM + 3 * A_DIM * F_DIM) * sizeof(float) +
        (size_t)F_DIM * VT_LD * sizeof(unsigned short) +
        (size_t)NKG * T_DIM * F_DIM * sizeof(float);
    const bool plain = (ws_size >= plain_need);

    zero_kernel<<<2048, 256, 0, stream>>>((float4*)out, out_size / 4);

    mlp12_kernel<<<dim3(A_DIM / 4, 3), 512, 0, stream>>>(feat0, w1, b1, w2, b2, h2ws);
    mlp3_kernel<<<dim3(A_DIM / 4, 2, 3), 256, 0, stream>>>(h2ws, w3, b3, rbfws);

    if (plain) {
        unsigned short* Vt = (unsigned short*)(h2ws + 3 * A_DIM * F_DIM);
        float* partial = (float*)(Vt + (size_t)F_DIM * VT_LD);
        build_vt_kernel<<<dim3(A_DIM, 9), 128, 0, stream>>>(feat0, feat1, feat2, rbfws, Vt);
        gemm_kernel<0><<<dim3(T_DIM / BT, A_DIM / 4), 256, 0, stream>>>(
            sph0, sph1, sph2, radial, Vt, partial);
        scatter_sum_kernel<<<dim3(T_DIM / 2), 256, 0, stream>>>(partial, tidx, out);
    } else {
        // Fallback layout: rbfws | h2ws | sparse | Vt
        float* sparse = h2ws + 3 * A_DIM * F_DIM;
        unsigned short* Vt = (unsigned short*)(sparse + T_DIM * F_DIM);
        hipMemsetAsync(sparse, 0, (size_t)T_DIM * F_DIM * sizeof(float), stream);
        build_vt_kernel<<<dim3(A_DIM, 9), 128, 0, stream>>>(feat0, feat1, feat2, rbfws, Vt);
        gemm_kernel<1><<<dim3(T_DIM / BT, A_DIM / 4), 256, 0, stream>>>(
            sph0, sph1, sph2, radial, Vt, sparse);
        scatter_kernel<<<dim3(T_DIM / 2), 256, 0, stream>>>(sparse, tidx, out);
    }
}

// Round 12
// 70.151 us; speedup vs baseline: 1.3165x; 1.0621x over previous
//
#include <hip/hip_runtime.h>
#include <hip/hip_bf16.h>
#include <cstdint>
#include <cstddef>

#define A_DIM 128
#define T_DIM 2048
#define F_DIM 128
#define RBF_DIM 16
#define KDD 2048              // K-span per dd block (128 atoms x 16 rbf)
#define VT_LD 18432           // Vt row stride = 9 * KDD
#define NKG 32                // K-groups (A_DIM / 4)
#define BT 64                 // t-span per gemm block

typedef __attribute__((ext_vector_type(8))) short short8;
typedef __attribute__((ext_vector_type(4))) float f32x4;
typedef __attribute__((ext_vector_type(4))) unsigned int u32x4;

__device__ __forceinline__ float silu_f(float x) {
    return x / (1.0f + __expf(-x));
}

// f2bf (RNE bit-twiddle) kept for build_vt; gemm A-build now uses
// v_cvt_pk_bf16_f32 (also RNE, 1 op per 2 elements).
__device__ __forceinline__ unsigned short f2bf(float x) {
    union { float f; unsigned u; } v; v.f = x;
    unsigned r = v.u + 0x7FFFu + ((v.u >> 16) & 1u);
    return (unsigned short)(r >> 16);
}

// async global->LDS, 16 B per lane; LDS dest is wave-uniform base + lane*16.
__device__ __forceinline__ void gl_lds16(const void* g, void* l) {
    __builtin_amdgcn_global_load_lds(
        (const __attribute__((address_space(1))) void*)g,
        (__attribute__((address_space(3))) void*)l, 16, 0, 0);
}

// Grid-stride float4 zero for d_out.
__global__ void zero_kernel(float4* __restrict__ p, int n4) {
    const int stride = gridDim.x * blockDim.x;
    const float4 z = {0.f, 0.f, 0.f, 0.f};
    for (int i = blockIdx.x * blockDim.x + threadIdx.x; i < n4; i += stride)
        p[i] = z;
}

// grid (A/4, 3), block 512. h1/h2 MLP layers for 4 atoms, one output/thread/layer.
__global__ void mlp12_kernel(const float* __restrict__ feat0,
                             const float* __restrict__ w1, const float* __restrict__ b1,
                             const float* __restrict__ w2, const float* __restrict__ b2,
                             float* __restrict__ h2ws) {
    __shared__ float inv_s[4 * F_DIM];
    __shared__ float h_s[4 * F_DIM];
    const int i  = blockIdx.y;
    const int a0 = blockIdx.x * 4;
    const int tid = threadIdx.x;
    const int f  = tid & 127;
    const int la = tid >> 7;

    inv_s[tid] = feat0[(a0 + la) * F_DIM + f];
    __syncthreads();

    const float* w1i = w1 + (size_t)i * F_DIM * F_DIM;
    float x = b1[i * F_DIM + f];
    #pragma unroll 8
    for (int k = 0; k < F_DIM; ++k)
        x = fmaf(inv_s[la * F_DIM + k], w1i[k * F_DIM + f], x);
    h_s[tid] = silu_f(x);
    __syncthreads();

    const float* w2i = w2 + (size_t)i * F_DIM * F_DIM;
    float y = b2[i * F_DIM + f];
    #pragma unroll 8
    for (int k = 0; k < F_DIM; ++k)
        y = fmaf(h_s[la * F_DIM + k], w2i[k * F_DIM + f], y);
    h2ws[((size_t)i * A_DIM + a0 + la) * F_DIM + f] = silu_f(y);
}

// grid (A/4, 2, 3), block 256. Layer 3: (4 atoms)x(1024 cols) tile, 4x4 register tile.
__global__ void mlp3_kernel(const float* __restrict__ h2ws,
                            const float* __restrict__ w3, const float* __restrict__ b3,
                            float* __restrict__ rbfws) {
    __shared__ float h2_s[4 * F_DIM];
    const int i  = blockIdx.z;
    const int a0 = blockIdx.x * 4;
    const int c0 = blockIdx.y * 1024;
    const int tid = threadIdx.x;

    for (int j = tid; j < 4 * F_DIM; j += 256)
        h2_s[j] = h2ws[((size_t)i * A_DIM + a0) * F_DIM + j];
    __syncthreads();

    const int c = c0 + tid * 4;
    const float* w3i = w3 + (size_t)i * F_DIM * 2048;
    float val[4][4];
    #pragma unroll
    for (int a = 0; a < 4; ++a) {
        #pragma unroll
        for (int cc = 0; cc < 4; ++cc)
            val[a][cc] = b3[i * 2048 + c + cc];
    }
    for (int k = 0; k < F_DIM; ++k) {
        const float4 w = *reinterpret_cast<const float4*>(&w3i[(size_t)k * 2048 + c]);
        #pragma unroll
        for (int a = 0; a < 4; ++a) {
            const float h = h2_s[a * F_DIM + k];
            val[a][0] = fmaf(h, w.x, val[a][0]);
            val[a][1] = fmaf(h, w.y, val[a][1]);
            val[a][2] = fmaf(h, w.z, val[a][2]);
            val[a][3] = fmaf(h, w.w, val[a][3]);
        }
    }
    const float inv_rbf = 0.25f;  // 1/sqrt(16)
    #pragma unroll
    for (int a = 0; a < 4; ++a) {
        float4 o;
        o.x = val[a][0] * inv_rbf;
        o.y = val[a][1] * inv_rbf;
        o.z = val[a][2] * inv_rbf;
        o.w = val[a][3] * inv_rbf;
        *reinterpret_cast<float4*>(&rbfws[((size_t)i * A_DIM + a0 + a) * 2048 + c]) = o;
    }
}

// Build Vt[f][k] bf16, k = dd*2048 + n*16 + r. (R4-exact.)
__global__ void build_vt_kernel(const float* __restrict__ feat0,
                                const float* __restrict__ feat1,
                                const float* __restrict__ feat2,
                                const float* __restrict__ rbfws,
                                unsigned short* __restrict__ Vt) {
    const int n  = blockIdx.x;
    const int dd = blockIdx.y;
    const int f  = threadIdx.x;

    int i, d;
    float fv;
    if (dd == 0)      { i = 0; d = 0;      fv = feat0[n * F_DIM + f]; }
    else if (dd < 4)  { i = 1; d = dd - 1; fv = feat1[(n * F_DIM + f) * 3 + d]; }
    else              { i = 2; d = dd - 4; fv = feat2[(n * F_DIM + f) * 5 + d]; }

    const float* rb = rbfws + ((size_t)(i * A_DIM + n) * RBF_DIM) * F_DIM + f;
    unsigned short* vp = Vt + (size_t)f * VT_LD + (size_t)dd * KDD + n * 16;
    #pragma unroll
    for (int r = 0; r < RBF_DIM; ++r)
        vp[r] = f2bf(fv * rb[(size_t)r * F_DIM]);
}

// MFMA GEMM — R11 body with ONE change: A-fragment bf16 conversion via
// v_cvt_pk_bf16_f32 (RNE, 4 instrs/frag) instead of 8x f2bf bit-twiddle
// (~40 VALU ops/frag). The A-build was ~5:1 VALU:MFMA — the MfmaUtil cap.
// Monolithic dd-loop — template pipelines failed 3/3 (R5-R7); keep monolithic.
// grid (32 mt, 32 kg), block 256 = 4 waves in 2x2 (wave tile 32t x 64f).
template<int MODE>
__global__ void __launch_bounds__(256) gemm_kernel(
        const float* __restrict__ sph0, const float* __restrict__ sph1,
        const float* __restrict__ sph2, const float* __restrict__ radial,
        const unsigned short* __restrict__ Vt,
        float* __restrict__ outbuf) {
    __shared__ unsigned short b_s[F_DIM * 64];   // 16 KB: [f][chunk^(f&7)] 8-elem chunks
    __shared__ float sph_s[4 * BT];              // 1 KB: [nn][tt]

    const int tid  = threadIdx.x;
    const int lane = tid & 63;
    const int w    = tid >> 6;
    const int wr   = w >> 1;            // wave row (t)
    const int wc   = w & 1;             // wave col (f)
    const int t0   = blockIdx.x * BT + wr * 32;
    const int n0   = blockIdx.y * 4;
    const int kq   = lane >> 4;         // 0..3
    const int lf   = lane & 15;

    // radial is dd-invariant: preload once to regs.
    // k_local = 32*ks + 8*kq + j -> atom n0 + 2*ks + (kq>>1), r = (kq&1)*8 + j.
    f32x4 rad[2][2][2];
    #pragma unroll
    for (int m = 0; m < 2; ++m) {
        const int t = t0 + 16 * m + lf;
        #pragma unroll
        for (int ks = 0; ks < 2; ++ks) {
            const int n = n0 + 2 * ks + (kq >> 1);
            const float* rp = radial + ((size_t)n * T_DIM + t) * 16 + (kq & 1) * 8;
            rad[m][ks][0] = *reinterpret_cast<const f32x4*>(rp);
            rad[m][ks][1] = *reinterpret_cast<const f32x4*>(rp + 4);
        }
    }

    // B staging source: per issue q, row f = q*32 + tid/8, chunk c' = (tid%8)^((tid/8)&7)
    const int fs_row = tid >> 3;
    const int cs     = (tid & 7) ^ ((tid >> 3) & 7);
    const unsigned short* gsrc0 = Vt + (size_t)fs_row * VT_LD + n0 * 16 + cs * 8;
    // sph staging: thread tid -> sph_s[nn*BT+tt]
    const int nn_s = tid >> 6;
    const int tt_s = tid & 63;
    const size_t sph_tbase = (size_t)(n0 + nn_s) * T_DIM + blockIdx.x * BT + tt_s;

    f32x4 acc[2][4];
    #pragma unroll
    for (int m = 0; m < 2; ++m)
        #pragma unroll
        for (int nf = 0; nf < 4; ++nf)
            acc[m][nf] = (f32x4){0.f, 0.f, 0.f, 0.f};

    #pragma unroll 1
    for (int dd = 0; dd < 9; ++dd) {
        const float* sp; int smul, soff;
        if (dd == 0)     { sp = sph0; smul = 1; soff = 0; }
        else if (dd < 4) { sp = sph1; smul = 3; soff = dd - 1; }
        else             { sp = sph2; smul = 5; soff = dd - 4; }

        __syncthreads();   // previous iteration done reading LDS

        // stage B-tile: 4 issues x (256 lanes x 16 B) = 16 KB, linear LDS dest
        const size_t koff = (size_t)dd * KDD;
        #pragma unroll
        for (int q = 0; q < 4; ++q) {
            const unsigned short* gp = gsrc0 + koff + (size_t)(q * 32) * VT_LD;
            void* lp = (void*)((char*)b_s + q * 4096 + w * 1024);
            gl_lds16(gp, lp);
        }
        // stage sph tile (256 floats)
        sph_s[tid] = sp[sph_tbase * smul + soff];

        __syncthreads();   // drains vmcnt+lgkmcnt before s_barrier

        // B-fragments from LDS (swizzled read): chunk cw = 4*ks+kq at row f
        short8 bfr[2][4];
        #pragma unroll
        for (int ks = 0; ks < 2; ++ks) {
            #pragma unroll
            for (int nf = 0; nf < 4; ++nf) {
                const int f = wc * 64 + 16 * nf + lf;
                const int byte = f * 128 + (((ks * 4 + kq) ^ (lf & 7)) * 16);
                bfr[ks][nf] = *reinterpret_cast<const short8*>((const char*)b_s + byte);
            }
        }

        // A-fragments: 8 products + 4 v_cvt_pk_bf16_f32 (low<-S0, high<-S1;
        // a[2d]=S0, a[2d+1]=S1 matches k-order), then 16x16x32 MFMAs.
        #pragma unroll
        for (int m = 0; m < 2; ++m) {
            #pragma unroll
            for (int ks = 0; ks < 2; ++ks) {
                const float s = sph_s[(2 * ks + (kq >> 1)) * BT + wr * 32 + 16 * m + lf];
                unsigned int d0, d1, d2, d3;
                asm("v_cvt_pk_bf16_f32 %0, %1, %2" : "=v"(d0)
                    : "v"(s * rad[m][ks][0][0]), "v"(s * rad[m][ks][0][1]));
                asm("v_cvt_pk_bf16_f32 %0, %1, %2" : "=v"(d1)
                    : "v"(s * rad[m][ks][0][2]), "v"(s * rad[m][ks][0][3]));
                asm("v_cvt_pk_bf16_f32 %0, %1, %2" : "=v"(d2)
                    : "v"(s * rad[m][ks][1][0]), "v"(s * rad[m][ks][1][1]));
                asm("v_cvt_pk_bf16_f32 %0, %1, %2" : "=v"(d3)
                    : "v"(s * rad[m][ks][1][2]), "v"(s * rad[m][ks][1][3]));
                union { u32x4 u; short8 s8; } au;
                au.u = (u32x4){d0, d1, d2, d3};
                #pragma unroll
                for (int nf = 0; nf < 4; ++nf)
                    acc[m][nf] = __builtin_amdgcn_mfma_f32_16x16x32_bf16(
                        au.s8, bfr[ks][nf], acc[m][nf], 0, 0, 0);
            }
        }
    }

    // Epilogue. C/D layout col=lane&15, row=(lane>>4)*4+reg (HW-verified in R4).
    float* pb = (MODE == 0)
        ? outbuf + (size_t)blockIdx.y * (T_DIM * F_DIM)   // own slice, plain stores
        : outbuf;                                          // shared, atomics
    #pragma unroll
    for (int m = 0; m < 2; ++m) {
        #pragma unroll
        for (int nf = 0; nf < 4; ++nf) {
            const int f = wc * 64 + 16 * nf + lf;
            #pragma unroll
            for (int reg = 0; reg < 4; ++reg) {
                const int t = t0 + 16 * m + 4 * kq + reg;
                if (MODE == 0)
                    pb[(size_t)t * F_DIM + f] = acc[m][nf][reg];
                else
                    atomicAdd(&pb[(size_t)t * F_DIM + f], acc[m][nf][reg]);
            }
        }
    }
}

// Plain path: sum 32 partial slices, then indexed atomicAdd into out.
__global__ void scatter_sum_kernel(const float* __restrict__ partial,
                                   const int* __restrict__ tidx,
                                   float* __restrict__ out) {
    const int tid = threadIdx.x;
    const int t = blockIdx.x * 2 + (tid >> 7);
    const int f = tid & 127;
    const int g = tidx[t];
    const float* p = partial + (size_t)t * F_DIM + f;
    float s = 0.0f;
    #pragma unroll
    for (int kg = 0; kg < NKG; ++kg)
        s += p[(size_t)kg * (T_DIM * F_DIM)];
    atomicAdd(&out[(size_t)g * F_DIM + f], s);
}

// Fallback path: scatter sparse rows into d_out.
__global__ void scatter_kernel(const float* __restrict__ sparse,
                               const int* __restrict__ tidx,
                               float* __restrict__ out) {
    const int tid = threadIdx.x;
    const int t = blockIdx.x * 2 + (tid >> 7);
    const int f = tid & 127;
    const int g = tidx[t];
    atomicAdd(&out[(size_t)g * F_DIM + f], sparse[(size_t)t * F_DIM + f]);
}

extern "C" void kernel_launch(void* const* d_in, const int* in_sizes, int n_in,
                              void* d_out, int out_size, void* d_ws, size_t ws_size,
                              hipStream_t stream) {
    const float* feat0  = (const float*)d_in[0];
    const float* feat1  = (const float*)d_in[1];
    const float* feat2  = (const float*)d_in[2];
    const float* sph0   = (const float*)d_in[3];
    const float* sph1   = (const float*)d_in[4];
    const float* sph2   = (const float*)d_in[5];
    const float* radial = (const float*)d_in[6];
    const float* w1     = (const float*)d_in[7];
    const float* b1     = (const float*)d_in[8];
    const float* w2     = (const float*)d_in[9];
    const float* b2     = (const float*)d_in[10];
    const float* w3     = (const float*)d_in[11];
    const float* b3     = (const float*)d_in[12];
    const int*   tidx   = (const int*)d_in[13];
    float* out = (float*)d_out;

    // Common ws prefix: rbfws 3 MB | h2ws 192 KB
    float* rbfws  = (float*)d_ws;
    float* h2ws   = rbfws + 3 * A_DIM * RBF_DIM * F_DIM;

    // Plain path needs: prefix + Vt (4.5 MB) + partial (32 MB) ~= 41.7 MB
    const size_t plain_need =
        (size_t)(3 * A_DIM * RBF_DIM * F_DIM + 3 * A_DIM * F_DIM) * sizeof(float) +
        (size_t)F_DIM * VT_LD * sizeof(unsigned short) +
        (size_t)NKG * T_DIM * F_DIM * sizeof(float);
    const bool plain = (ws_size >= plain_need);

    zero_kernel<<<2048, 256, 0, stream>>>((float4*)out, out_size / 4);

    mlp12_kernel<<<dim3(A_DIM / 4, 3), 512, 0, stream>>>(feat0, w1, b1, w2, b2, h2ws);
    mlp3_kernel<<<dim3(A_DIM / 4, 2, 3), 256, 0, stream>>>(h2ws, w3, b3, rbfws);

    if (plain) {
        unsigned short* Vt = (unsigned short*)(h2ws + 3 * A_DIM * F_DIM);
        float* partial = (float*)(Vt + (size_t)F_DIM * VT_LD);
        build_vt_kernel<<<dim3(A_DIM, 9), 128, 0, stream>>>(feat0, feat1, feat2, rbfws, Vt);
        gemm_kernel<0><<<dim3(T_DIM / BT, A_DIM / 4), 256, 0, stream>>>(
            sph0, sph1, sph2, radial, Vt, partial);
        scatter_sum_kernel<<<dim3(T_DIM / 2), 256, 0, stream>>>(partial, tidx, out);
    } else {
        // Fallback layout: rbfws | h2ws | sparse | Vt
        float* sparse = h2ws + 3 * A_DIM * F_DIM;
        unsigned short* Vt = (unsigned short*)(sparse + T_DIM * F_DIM);
        hipMemsetAsync(sparse, 0, (size_t)T_DIM * F_DIM * sizeof(float), stream);
        build_vt_kernel<<<dim3(A_DIM, 9), 128, 0, stream>>>(feat0, feat1, feat2, rbfws, Vt);
        gemm_kernel<1><<<dim3(T_DIM / BT, A_DIM / 4), 256, 0, stream>>>(
            sph0, sph1, sph2, radial, Vt, sparse);
        scatter_kernel<<<dim3(T_DIM / 2), 256, 0, stream>>>(sparse, tidx, out);
    }
}

// Round 13
// 63.726 us; speedup vs baseline: 1.4492x; 1.1008x over previous
//
#include <hip/hip_runtime.h>
#include <hip/hip_bf16.h>
#include <cstdint>
#include <cstddef>

#define A_DIM 128
#define T_DIM 2048
#define F_DIM 128
#define RBF_DIM 16
#define KDD 2048              // K-span per dd block (128 atoms x 16 rbf)
#define VT_LD 18432           // Vt row stride = 9 * KDD
#define NKG 32                // K-groups (A_DIM / 4)
#define BT 64                 // t-span per gemm block

typedef __attribute__((ext_vector_type(8))) short short8;
typedef __attribute__((ext_vector_type(4))) float f32x4;
typedef __attribute__((ext_vector_type(4))) unsigned int u32x4;

__device__ __forceinline__ float silu_f(float x) {
    return x / (1.0f + __expf(-x));
}

// f2bf (RNE bit-twiddle) for build_vt; gemm A-build uses v_cvt_pk_bf16_f32
// (also RNE). Do NOT swap for __float2bfloat16.
__device__ __forceinline__ unsigned short f2bf(float x) {
    union { float f; unsigned u; } v; v.f = x;
    unsigned r = v.u + 0x7FFFu + ((v.u >> 16) & 1u);
    return (unsigned short)(r >> 16);
}

// async global->LDS, 16 B per lane; LDS dest is wave-uniform base + lane*16.
__device__ __forceinline__ void gl_lds16(const void* g, void* l) {
    __builtin_amdgcn_global_load_lds(
        (const __attribute__((address_space(1))) void*)g,
        (__attribute__((address_space(3))) void*)l, 16, 0, 0);
}

// Grid-stride float4 zero (fallback path only; plain path zeroes in gemm).
__global__ void zero_kernel(float4* __restrict__ p, int n4) {
    const int stride = gridDim.x * blockDim.x;
    const float4 z = {0.f, 0.f, 0.f, 0.f};
    for (int i = blockIdx.x * blockDim.x + threadIdx.x; i < n4; i += stride)
        p[i] = z;
}

// Fused MLP: layers 1+2 (mlp12-exact, h2 via LDS) + layer 3 (mlp3-exact
// val[4][4] register tile, c = tid*4 covers all 2048 cols at block 512).
// grid (A/4, 3), block 512. Saves the h2ws global round-trip + one launch.
__global__ void mlp_fused_kernel(const float* __restrict__ feat0,
                                 const float* __restrict__ w1, const float* __restrict__ b1,
                                 const float* __restrict__ w2, const float* __restrict__ b2,
                                 const float* __restrict__ w3, const float* __restrict__ b3,
                                 float* __restrict__ rbfws) {
    __shared__ float inv_s[4 * F_DIM];
    __shared__ float h_s[4 * F_DIM];
    __shared__ float h2_s[4 * F_DIM];
    const int i  = blockIdx.y;
    const int a0 = blockIdx.x * 4;
    const int tid = threadIdx.x;
    const int f  = tid & 127;
    const int la = tid >> 7;

    inv_s[tid] = feat0[(a0 + la) * F_DIM + f];
    __syncthreads();

    const float* w1i = w1 + (size_t)i * F_DIM * F_DIM;
    float x = b1[i * F_DIM + f];
    #pragma unroll 8
    for (int k = 0; k < F_DIM; ++k)
        x = fmaf(inv_s[la * F_DIM + k], w1i[k * F_DIM + f], x);
    h_s[tid] = silu_f(x);
    __syncthreads();

    const float* w2i = w2 + (size_t)i * F_DIM * F_DIM;
    float y = b2[i * F_DIM + f];
    #pragma unroll 8
    for (int k = 0; k < F_DIM; ++k)
        y = fmaf(h_s[la * F_DIM + k], w2i[k * F_DIM + f], y);
    h2_s[tid] = silu_f(y);   // tid == la*128 + f
    __syncthreads();

    // Layer 3 (mlp3-exact math): thread owns cols c..c+3 for 4 atoms.
    const int c = tid * 4;
    const float* w3i = w3 + (size_t)i * F_DIM * 2048;
    float val[4][4];
    #pragma unroll
    for (int a = 0; a < 4; ++a) {
        #pragma unroll
        for (int cc = 0; cc < 4; ++cc)
            val[a][cc] = b3[i * 2048 + c + cc];
    }
    for (int k = 0; k < F_DIM; ++k) {
        const float4 w = *reinterpret_cast<const float4*>(&w3i[(size_t)k * 2048 + c]);
        #pragma unroll
        for (int a = 0; a < 4; ++a) {
            const float h = h2_s[a * F_DIM + k];
            val[a][0] = fmaf(h, w.x, val[a][0]);
            val[a][1] = fmaf(h, w.y, val[a][1]);
            val[a][2] = fmaf(h, w.z, val[a][2]);
            val[a][3] = fmaf(h, w.w, val[a][3]);
        }
    }
    const float inv_rbf = 0.25f;  // 1/sqrt(16)
    #pragma unroll
    for (int a = 0; a < 4; ++a) {
        float4 o;
        o.x = val[a][0] * inv_rbf;
        o.y = val[a][1] * inv_rbf;
        o.z = val[a][2] * inv_rbf;
        o.w = val[a][3] * inv_rbf;
        *reinterpret_cast<float4*>(&rbfws[((size_t)i * A_DIM + a0 + a) * 2048 + c]) = o;
    }
}

// Build Vt[f][k] bf16, k = dd*2048 + n*16 + r. (R4-exact.)
__global__ void build_vt_kernel(const float* __restrict__ feat0,
                                const float* __restrict__ feat1,
                                const float* __restrict__ feat2,
                                const float* __restrict__ rbfws,
                                unsigned short* __restrict__ Vt) {
    const int n  = blockIdx.x;
    const int dd = blockIdx.y;
    const int f  = threadIdx.x;

    int i, d;
    float fv;
    if (dd == 0)      { i = 0; d = 0;      fv = feat0[n * F_DIM + f]; }
    else if (dd < 4)  { i = 1; d = dd - 1; fv = feat1[(n * F_DIM + f) * 3 + d]; }
    else              { i = 2; d = dd - 4; fv = feat2[(n * F_DIM + f) * 5 + d]; }

    const float* rb = rbfws + ((size_t)(i * A_DIM + n) * RBF_DIM) * F_DIM + f;
    unsigned short* vp = Vt + (size_t)f * VT_LD + (size_t)dd * KDD + n * 16;
    #pragma unroll
    for (int r = 0; r < RBF_DIM; ++r)
        vp[r] = f2bf(fv * rb[(size_t)r * F_DIM]);
}

// MFMA GEMM — R12 body with ONE addition: MODE 0 blocks zero their 32 KB
// slice of d_out in the prologue (33.5 MB of BW work overlapped under the
// compute loop; removes the standalone zero_kernel launch).
// Monolithic dd-loop — template pipelines failed 3/3 (R5-R7); keep monolithic.
// grid (32 mt, 32 kg), block 256 = 4 waves in 2x2 (wave tile 32t x 64f).
template<int MODE>
__global__ void __launch_bounds__(256) gemm_kernel(
        const float* __restrict__ sph0, const float* __restrict__ sph1,
        const float* __restrict__ sph2, const float* __restrict__ radial,
        const unsigned short* __restrict__ Vt,
        float* __restrict__ outbuf,
        float* __restrict__ dout, int out_n4) {
    __shared__ unsigned short b_s[F_DIM * 64];   // 16 KB: [f][chunk^(f&7)] 8-elem chunks
    __shared__ float sph_s[4 * BT];              // 1 KB: [nn][tt]

    const int tid  = threadIdx.x;
    const int lane = tid & 63;
    const int w    = tid >> 6;
    const int wr   = w >> 1;            // wave row (t)
    const int wc   = w & 1;             // wave col (f)
    const int t0   = blockIdx.x * BT + wr * 32;
    const int n0   = blockIdx.y * 4;
    const int kq   = lane >> 4;         // 0..3
    const int lf   = lane & 15;

    // Prologue: zero this block's slice of d_out (plain path only).
    if (MODE == 0) {
        const int bid = blockIdx.y * gridDim.x + blockIdx.x;     // 0..1023
        const float4 z = {0.f, 0.f, 0.f, 0.f};
        float4* zp = (float4*)dout;
        #pragma unroll
        for (int q = 0; q < 8; ++q) {
            const int idx = bid * 2048 + q * 256 + tid;
            if (idx < out_n4) zp[idx] = z;
        }
    }

    // radial is dd-invariant: preload once to regs.
    // k_local = 32*ks + 8*kq + j -> atom n0 + 2*ks + (kq>>1), r = (kq&1)*8 + j.
    f32x4 rad[2][2][2];
    #pragma unroll
    for (int m = 0; m < 2; ++m) {
        const int t = t0 + 16 * m + lf;
        #pragma unroll
        for (int ks = 0; ks < 2; ++ks) {
            const int n = n0 + 2 * ks + (kq >> 1);
            const float* rp = radial + ((size_t)n * T_DIM + t) * 16 + (kq & 1) * 8;
            rad[m][ks][0] = *reinterpret_cast<const f32x4*>(rp);
            rad[m][ks][1] = *reinterpret_cast<const f32x4*>(rp + 4);
        }
    }

    // B staging source: per issue q, row f = q*32 + tid/8, chunk c' = (tid%8)^((tid/8)&7)
    const int fs_row = tid >> 3;
    const int cs     = (tid & 7) ^ ((tid >> 3) & 7);
    const unsigned short* gsrc0 = Vt + (size_t)fs_row * VT_LD + n0 * 16 + cs * 8;
    // sph staging: thread tid -> sph_s[nn*BT+tt]
    const int nn_s = tid >> 6;
    const int tt_s = tid & 63;
    const size_t sph_tbase = (size_t)(n0 + nn_s) * T_DIM + blockIdx.x * BT + tt_s;

    f32x4 acc[2][4];
    #pragma unroll
    for (int m = 0; m < 2; ++m)
        #pragma unroll
        for (int nf = 0; nf < 4; ++nf)
            acc[m][nf] = (f32x4){0.f, 0.f, 0.f, 0.f};

    #pragma unroll 1
    for (int dd = 0; dd < 9; ++dd) {
        const float* sp; int smul, soff;
        if (dd == 0)     { sp = sph0; smul = 1; soff = 0; }
        else if (dd < 4) { sp = sph1; smul = 3; soff = dd - 1; }
        else             { sp = sph2; smul = 5; soff = dd - 4; }

        __syncthreads();   // previous iteration done reading LDS

        // stage B-tile: 4 issues x (256 lanes x 16 B) = 16 KB, linear LDS dest
        const size_t koff = (size_t)dd * KDD;
        #pragma unroll
        for (int q = 0; q < 4; ++q) {
            const unsigned short* gp = gsrc0 + koff + (size_t)(q * 32) * VT_LD;
            void* lp = (void*)((char*)b_s + q * 4096 + w * 1024);
            gl_lds16(gp, lp);
        }
        // stage sph tile (256 floats)
        sph_s[tid] = sp[sph_tbase * smul + soff];

        __syncthreads();   // drains vmcnt+lgkmcnt before s_barrier

        // B-fragments from LDS (swizzled read): chunk cw = 4*ks+kq at row f
        short8 bfr[2][4];
        #pragma unroll
        for (int ks = 0; ks < 2; ++ks) {
            #pragma unroll
            for (int nf = 0; nf < 4; ++nf) {
                const int f = wc * 64 + 16 * nf + lf;
                const int byte = f * 128 + (((ks * 4 + kq) ^ (lf & 7)) * 16);
                bfr[ks][nf] = *reinterpret_cast<const short8*>((const char*)b_s + byte);
            }
        }

        // A-fragments: 8 products + 4 v_cvt_pk_bf16_f32 (RNE; low<-S0, high<-S1),
        // then 16x16x32 MFMAs.
        #pragma unroll
        for (int m = 0; m < 2; ++m) {
            #pragma unroll
            for (int ks = 0; ks < 2; ++ks) {
                const float s = sph_s[(2 * ks + (kq >> 1)) * BT + wr * 32 + 16 * m + lf];
                unsigned int d0, d1, d2, d3;
                asm("v_cvt_pk_bf16_f32 %0, %1, %2" : "=v"(d0)
                    : "v"(s * rad[m][ks][0][0]), "v"(s * rad[m][ks][0][1]));
                asm("v_cvt_pk_bf16_f32 %0, %1, %2" : "=v"(d1)
                    : "v"(s * rad[m][ks][0][2]), "v"(s * rad[m][ks][0][3]));
                asm("v_cvt_pk_bf16_f32 %0, %1, %2" : "=v"(d2)
                    : "v"(s * rad[m][ks][1][0]), "v"(s * rad[m][ks][1][1]));
                asm("v_cvt_pk_bf16_f32 %0, %1, %2" : "=v"(d3)
                    : "v"(s * rad[m][ks][1][2]), "v"(s * rad[m][ks][1][3]));
                union { u32x4 u; short8 s8; } au;
                au.u = (u32x4){d0, d1, d2, d3};
                #pragma unroll
                for (int nf = 0; nf < 4; ++nf)
                    acc[m][nf] = __builtin_amdgcn_mfma_f32_16x16x32_bf16(
                        au.s8, bfr[ks][nf], acc[m][nf], 0, 0, 0);
            }
        }
    }

    // Epilogue. C/D layout col=lane&15, row=(lane>>4)*4+reg (HW-verified in R4).
    float* pb = (MODE == 0)
        ? outbuf + (size_t)blockIdx.y * (T_DIM * F_DIM)   // own slice, plain stores
        : outbuf;                                          // shared, atomics
    #pragma unroll
    for (int m = 0; m < 2; ++m) {
        #pragma unroll
        for (int nf = 0; nf < 4; ++nf) {
            const int f = wc * 64 + 16 * nf + lf;
            #pragma unroll
            for (int reg = 0; reg < 4; ++reg) {
                const int t = t0 + 16 * m + 4 * kq + reg;
                if (MODE == 0)
                    pb[(size_t)t * F_DIM + f] = acc[m][nf][reg];
                else
                    atomicAdd(&pb[(size_t)t * F_DIM + f], acc[m][nf][reg]);
            }
        }
    }
}

// Plain path: sum 32 partial slices, then indexed atomicAdd into out.
__global__ void scatter_sum_kernel(const float* __restrict__ partial,
                                   const int* __restrict__ tidx,
                                   float* __restrict__ out) {
    const int tid = threadIdx.x;
    const int t = blockIdx.x * 2 + (tid >> 7);
    const int f = tid & 127;
    const int g = tidx[t];
    const float* p = partial + (size_t)t * F_DIM + f;
    float s = 0.0f;
    #pragma unroll
    for (int kg = 0; kg < NKG; ++kg)
        s += p[(size_t)kg * (T_DIM * F_DIM)];
    atomicAdd(&out[(size_t)g * F_DIM + f], s);
}

// Fallback path: scatter sparse rows into d_out.
__global__ void scatter_kernel(const float* __restrict__ sparse,
                               const int* __restrict__ tidx,
                               float* __restrict__ out) {
    const int tid = threadIdx.x;
    const int t = blockIdx.x * 2 + (tid >> 7);
    const int f = tid & 127;
    const int g = tidx[t];
    atomicAdd(&out[(size_t)g * F_DIM + f], sparse[(size_t)t * F_DIM + f]);
}

extern "C" void kernel_launch(void* const* d_in, const int* in_sizes, int n_in,
                              void* d_out, int out_size, void* d_ws, size_t ws_size,
                              hipStream_t stream) {
    const float* feat0  = (const float*)d_in[0];
    const float* feat1  = (const float*)d_in[1];
    const float* feat2  = (const float*)d_in[2];
    const float* sph0   = (const float*)d_in[3];
    const float* sph1   = (const float*)d_in[4];
    const float* sph2   = (const float*)d_in[5];
    const float* radial = (const float*)d_in[6];
    const float* w1     = (const float*)d_in[7];
    const float* b1     = (const float*)d_in[8];
    const float* w2     = (const float*)d_in[9];
    const float* b2     = (const float*)d_in[10];
    const float* w3     = (const float*)d_in[11];
    const float* b3     = (const float*)d_in[12];
    const int*   tidx   = (const int*)d_in[13];
    float* out = (float*)d_out;

    // Common ws prefix: rbfws 3 MB | h2ws slot kept for layout stability
    float* rbfws  = (float*)d_ws;
    float* h2ws   = rbfws + 3 * A_DIM * RBF_DIM * F_DIM;

    // Plain path needs: prefix + Vt (4.5 MB) + partial (32 MB) ~= 41.7 MB
    const size_t plain_need =
        (size_t)(3 * A_DIM * RBF_DIM * F_DIM + 3 * A_DIM * F_DIM) * sizeof(float) +
        (size_t)F_DIM * VT_LD * sizeof(unsigned short) +
        (size_t)NKG * T_DIM * F_DIM * sizeof(float);
    const bool plain = (ws_size >= plain_need);

    mlp_fused_kernel<<<dim3(A_DIM / 4, 3), 512, 0, stream>>>(
        feat0, w1, b1, w2, b2, w3, b3, rbfws);

    if (plain) {
        unsigned short* Vt = (unsigned short*)(h2ws + 3 * A_DIM * F_DIM);
        float* partial = (float*)(Vt + (size_t)F_DIM * VT_LD);
        build_vt_kernel<<<dim3(A_DIM, 9), 128, 0, stream>>>(feat0, feat1, feat2, rbfws, Vt);
        gemm_kernel<0><<<dim3(T_DIM / BT, A_DIM / 4), 256, 0, stream>>>(
            sph0, sph1, sph2, radial, Vt, partial, out, out_size / 4);
        scatter_sum_kernel<<<dim3(T_DIM / 2), 256, 0, stream>>>(partial, tidx, out);
    } else {
        // Fallback layout: rbfws | h2ws | sparse | Vt
        float* sparse = h2ws + 3 * A_DIM * F_DIM;
        unsigned short* Vt = (unsigned short*)(sparse + T_DIM * F_DIM);
        zero_kernel<<<2048, 256, 0, stream>>>((float4*)out, out_size / 4);
        hipMemsetAsync(sparse, 0, (size_t)T_DIM * F_DIM * sizeof(float), stream);
        build_vt_kernel<<<dim3(A_DIM, 9), 128, 0, stream>>>(feat0, feat1, feat2, rbfws, Vt);
        gemm_kernel<1><<<dim3(T_DIM / BT, A_DIM / 4), 256, 0, stream>>>(
            sph0, sph1, sph2, radial, Vt, sparse, out, out_size / 4);
        scatter_kernel<<<dim3(T_DIM / 2), 256, 0, stream>>>(sparse, tidx, out);
    }
}